// Round 1
// baseline (412.165 us; speedup 1.0000x reference)
//
#include <hip/hip_runtime.h>

#define NDIM 64   // D
#define FDIM 128  // 2D

// Transpose W1 [64][128] (row-major, h = f @ W1^T) into W1T [128][64] so the
// main kernel reads a contiguous 64-float column per k (wave-uniform -> s_load).
__global__ void w1_transpose_kernel(const float* __restrict__ W1,
                                    float* __restrict__ W1T) {
    int i = blockIdx.x * blockDim.x + threadIdx.x;
    if (i < NDIM * FDIM) {
        int j = i >> 7;      // row in W1 (output unit), / 128
        int k = i & 127;     // col in W1 (input feature)
        W1T[k * NDIM + j] = W1[i];
    }
}

__global__ __launch_bounds__(256) void edge_mlp_kernel(
    const float* __restrict__ x,     // [N,64]
    const int*   __restrict__ ei,    // [2,E] flat
    const float* __restrict__ W1T,   // [128][64]
    const float* __restrict__ b1,    // [64]
    const float* __restrict__ W2,    // [64]
    const float* __restrict__ b2,    // [1]
    float*       __restrict__ out,   // [E]
    int E)
{
    int e = blockIdx.x * blockDim.x + threadIdx.x;
    if (e >= E) return;

    int s = ei[e];
    int d = ei[E + e];
    const float4* xs = (const float4*)(x + (size_t)s * NDIM);
    const float4* xd = (const float4*)(x + (size_t)d * NDIM);

    float h[NDIM];
    #pragma unroll
    for (int j = 0; j < NDIM; j++) h[j] = b1[j];

    // First half of features: x[src] (k = 0..63)
    #pragma unroll 1
    for (int k4 = 0; k4 < 16; k4++) {
        float4 f = xs[k4];
        const float* w = W1T + k4 * 4 * NDIM;   // wave-uniform address
        #pragma unroll
        for (int j = 0; j < NDIM; j++) {
            h[j] += w[j] * f.x + w[NDIM + j] * f.y
                  + w[2 * NDIM + j] * f.z + w[3 * NDIM + j] * f.w;
        }
    }
    // Second half: x[dst] (k = 64..127)
    #pragma unroll 1
    for (int k4 = 0; k4 < 16; k4++) {
        float4 f = xd[k4];
        const float* w = W1T + (16 + k4) * 4 * NDIM;
        #pragma unroll
        for (int j = 0; j < NDIM; j++) {
            h[j] += w[j] * f.x + w[NDIM + j] * f.y
                  + w[2 * NDIM + j] * f.z + w[3 * NDIM + j] * f.w;
        }
    }

    // Layer 2: out = b2 + W2 . relu(h)
    float acc = b2[0];
    #pragma unroll
    for (int j = 0; j < NDIM; j++) {
        float hj = h[j] > 0.f ? h[j] : 0.f;
        acc += W2[j] * hj;
    }
    out[e] = acc;
}

extern "C" void kernel_launch(void* const* d_in, const int* in_sizes, int n_in,
                              void* d_out, int out_size, void* d_ws, size_t ws_size,
                              hipStream_t stream) {
    const float* x   = (const float*)d_in[0];
    const int*   ei  = (const int*)d_in[1];
    const float* W1  = (const float*)d_in[2];
    const float* b1  = (const float*)d_in[3];
    const float* W2  = (const float*)d_in[4];
    const float* b2  = (const float*)d_in[5];
    float* out = (float*)d_out;
    float* W1T = (float*)d_ws;   // 128*64*4 = 32 KB scratch

    int E = out_size;  // 1e6 edges

    // d_ws is re-poisoned before every timed launch -> must rebuild W1T each call.
    w1_transpose_kernel<<<(NDIM * FDIM + 255) / 256, 256, 0, stream>>>(W1, W1T);

    int blocks = (E + 255) / 256;
    edge_mlp_kernel<<<blocks, 256, 0, stream>>>(x, ei, W1T, b1, W2, b2, out, E);
}

// Round 2
// 147.219 us; speedup vs baseline: 2.7997x; 2.7997x over previous
//
#include <hip/hip_runtime.h>

#define NDIM 64   // D
#define FDIM 128  // 2D

typedef _Float16 half8 __attribute__((ext_vector_type(8)));
typedef float    float4v __attribute__((ext_vector_type(4)));

// ---------------- fp32 fallback path (round-1 kernel, used if ws too small) ----
__global__ void w1_transpose_kernel(const float* __restrict__ W1,
                                    float* __restrict__ W1T) {
    int i = blockIdx.x * blockDim.x + threadIdx.x;
    if (i < NDIM * FDIM) {
        int j = i >> 7;
        int k = i & 127;
        W1T[k * NDIM + j] = W1[i];
    }
}

__global__ __launch_bounds__(256) void edge_mlp_fp32_kernel(
    const float* __restrict__ x, const int* __restrict__ ei,
    const float* __restrict__ W1T, const float* __restrict__ b1,
    const float* __restrict__ W2, const float* __restrict__ b2,
    float* __restrict__ out, int E)
{
    int e = blockIdx.x * blockDim.x + threadIdx.x;
    if (e >= E) return;
    int s = ei[e];
    int d = ei[E + e];
    const float4* xs = (const float4*)(x + (size_t)s * NDIM);
    const float4* xd = (const float4*)(x + (size_t)d * NDIM);
    float h[NDIM];
    #pragma unroll
    for (int j = 0; j < NDIM; j++) h[j] = b1[j];
    #pragma unroll 1
    for (int k4 = 0; k4 < 16; k4++) {
        float4 f = xs[k4];
        const float* w = W1T + k4 * 4 * NDIM;
        #pragma unroll
        for (int j = 0; j < NDIM; j++)
            h[j] += w[j] * f.x + w[NDIM + j] * f.y + w[2 * NDIM + j] * f.z + w[3 * NDIM + j] * f.w;
    }
    #pragma unroll 1
    for (int k4 = 0; k4 < 16; k4++) {
        float4 f = xd[k4];
        const float* w = W1T + (16 + k4) * 4 * NDIM;
        #pragma unroll
        for (int j = 0; j < NDIM; j++)
            h[j] += w[j] * f.x + w[NDIM + j] * f.y + w[2 * NDIM + j] * f.z + w[3 * NDIM + j] * f.w;
    }
    float acc = b2[0];
    #pragma unroll
    for (int j = 0; j < NDIM; j++) {
        float hj = h[j] > 0.f ? h[j] : 0.f;
        acc += W2[j] * hj;
    }
    out[e] = acc;
}

// ---------------- f16 MFMA path ----------------------------------------------

// Convert x [nx floats] and W1 [64*128 floats] to f16 in one launch.
// Threads [0, nx/8) handle x (8 elems each); the next 8192/8 threads handle W1.
__global__ __launch_bounds__(256) void convert_f16_kernel(
    const float* __restrict__ x, const float* __restrict__ W1,
    _Float16* __restrict__ xh, _Float16* __restrict__ W1h, int nx)
{
    int t = blockIdx.x * blockDim.x + threadIdx.x;
    int tx = nx >> 3;
    const float* src;
    _Float16* dst;
    int off;
    if (t < tx) { src = x; dst = xh; off = t * 8; }
    else {
        off = (t - tx) * 8;
        if (off >= NDIM * FDIM) return;
        src = W1; dst = W1h;
    }
    float4v f0 = *(const float4v*)(src + off);
    float4v f1 = *(const float4v*)(src + off + 4);
    half8 h;
    h[0] = (_Float16)f0[0]; h[1] = (_Float16)f0[1];
    h[2] = (_Float16)f0[2]; h[3] = (_Float16)f0[3];
    h[4] = (_Float16)f1[0]; h[5] = (_Float16)f1[1];
    h[6] = (_Float16)f1[2]; h[7] = (_Float16)f1[3];
    *(half8*)(dst + off) = h;
}

// One block = 256 edges; one wave = 64 edges (4 M-tiles of 16).
// GEMM: [64 edges x 128 feats] @ [128 x 64] via mfma_f32_16x16x32_f16.
// A-fragments gathered directly from global xh (one 128B line per row).
// B = W1h in its native [n=j][k] layout (L2-resident, 16 KB).
__global__ __launch_bounds__(256) void edge_mlp_mfma_kernel(
    const _Float16* __restrict__ xh,   // [N][64] f16
    const int* __restrict__ ei,        // [2E] int32
    const _Float16* __restrict__ W1h,  // [64][128] f16
    const float* __restrict__ b1,      // [64]
    const float* __restrict__ W2,      // [64]
    const float* __restrict__ b2,      // [1]
    float* __restrict__ out,           // [E]
    int E)
{
    const int wave = threadIdx.x >> 6;
    const int lane = threadIdx.x & 63;
    const int c = lane & 15;   // A: edge-in-tile | B/C: column j-in-tile
    const int g = lane >> 4;   // k-group (frag) / row-group (C)

    const long e0 = (long)blockIdx.x * 256 + wave * 64;
    if (e0 >= E) return;   // wave-uniform (E multiple of 64)

    // Edge indices for this lane's A rows (edge = e0 + mt*16 + c)
    int sidx[4], didx[4];
    #pragma unroll
    for (int mt = 0; mt < 4; mt++) {
        sidx[mt] = ei[e0 + mt * 16 + c];
        didx[mt] = ei[E + e0 + mt * 16 + c];
    }

    float4v C[4][4];
    #pragma unroll
    for (int mt = 0; mt < 4; mt++)
        #pragma unroll
        for (int nt = 0; nt < 4; nt++)
            C[mt][nt] = (float4v){0.f, 0.f, 0.f, 0.f};

    // K loop: kk = 0..3 covers feats kk*32..kk*32+31 (kk<2 -> src row, else dst)
    #pragma unroll
    for (int kk = 0; kk < 4; kk++) {
        const int koff = (kk & 1) * 32 + g * 8;  // offset within the 64-feat row
        half8 Af[4], Bf[4];
        #pragma unroll
        for (int mt = 0; mt < 4; mt++) {
            int idx = (kk < 2) ? sidx[mt] : didx[mt];
            Af[mt] = *(const half8*)(xh + (size_t)idx * NDIM + koff);
        }
        #pragma unroll
        for (int nt = 0; nt < 4; nt++)
            Bf[nt] = *(const half8*)(W1h + (nt * 16 + c) * FDIM + kk * 32 + g * 8);
        #pragma unroll
        for (int mt = 0; mt < 4; mt++)
            #pragma unroll
            for (int nt = 0; nt < 4; nt++)
                C[mt][nt] = __builtin_amdgcn_mfma_f32_16x16x32_f16(
                    Af[mt], Bf[nt], C[mt][nt], 0, 0, 0);
    }

    // Epilogue: out[e] = b2 + sum_j W2[j] * relu(h[e][j] + b1[j])
    // C layout (16x16): col j = c, edge row = g*4 + r.
    float b1v[4], w2v[4];
    #pragma unroll
    for (int nt = 0; nt < 4; nt++) {
        b1v[nt] = b1[nt * 16 + c];
        w2v[nt] = W2[nt * 16 + c];
    }
    const float b2v = b2[0];

    #pragma unroll
    for (int mt = 0; mt < 4; mt++) {
        float acc[4];
        #pragma unroll
        for (int r = 0; r < 4; r++) {
            float a = 0.f;
            #pragma unroll
            for (int nt = 0; nt < 4; nt++) {
                float h = C[mt][nt][r] + b1v[nt];
                h = h > 0.f ? h : 0.f;
                a += w2v[nt] * h;
            }
            acc[r] = a;
        }
        // reduce over the 16 column lanes (xor bits 0..3)
        #pragma unroll
        for (int mask = 1; mask < 16; mask <<= 1) {
            #pragma unroll
            for (int r = 0; r < 4; r++)
                acc[r] += __shfl_xor(acc[r], mask, 64);
        }
        if (c == 0) {
            float4v o;
            #pragma unroll
            for (int r = 0; r < 4; r++) o[r] = acc[r] + b2v;
            *(float4v*)(out + e0 + mt * 16 + g * 4) = o;
        }
    }
}

extern "C" void kernel_launch(void* const* d_in, const int* in_sizes, int n_in,
                              void* d_out, int out_size, void* d_ws, size_t ws_size,
                              hipStream_t stream) {
    const float* x  = (const float*)d_in[0];
    const int*   ei = (const int*)d_in[1];
    const float* W1 = (const float*)d_in[2];
    const float* b1 = (const float*)d_in[3];
    const float* W2 = (const float*)d_in[4];
    const float* b2 = (const float*)d_in[5];
    float* out = (float*)d_out;
    const int E = out_size;
    const int nx = in_sizes[0];                 // N*D floats

    const size_t xh_bytes = (size_t)nx * 2;
    const size_t need = xh_bytes + (size_t)NDIM * FDIM * 2;

    if (ws_size >= need && (nx & 7) == 0) {
        _Float16* xh  = (_Float16*)d_ws;
        _Float16* W1h = (_Float16*)((char*)d_ws + xh_bytes);

        const int conv_threads = (nx >> 3) + (NDIM * FDIM >> 3);
        const int conv_blocks = (conv_threads + 255) / 256;
        convert_f16_kernel<<<conv_blocks, 256, 0, stream>>>(x, W1, xh, W1h, nx);

        const int blocks = (E + 255) / 256;
        edge_mlp_mfma_kernel<<<blocks, 256, 0, stream>>>(xh, ei, W1h, b1, W2, b2, out, E);
    } else {
        float* W1T = (float*)d_ws;  // 32 KB
        w1_transpose_kernel<<<(NDIM * FDIM + 255) / 256, 256, 0, stream>>>(W1, W1T);
        const int blocks = (E + 255) / 256;
        edge_mlp_fp32_kernel<<<blocks, 256, 0, stream>>>(x, ei, W1T, b1, W2, b2, out, E);
    }
}